// Round 7
// baseline (99.974 us; speedup 1.0000x reference)
//
#include <hip/hip_runtime.h>
#include <cstddef>
#include <cstdint>

#define S_LEN 2048
#define D_DIM 512
#define NHEAD 4
#define DHEAD 128
#define BH_CNT 16
#define SCALE_QK 0.08838834764831845f

typedef _Float16 f16;
typedef _Float16 f16x8 __attribute__((ext_vector_type(8)));
typedef float f32x16 __attribute__((ext_vector_type(16)));

#define AS1 __attribute__((address_space(1)))
#define AS3 __attribute__((address_space(3)))

__device__ __forceinline__ unsigned pkh(float a, float b) {
  auto r = __builtin_amdgcn_cvt_pkrtz(a, b);   // __fp16 ext_vector_type(2)
  return __builtin_bit_cast(unsigned, r);
}

// ---------------- Kernel 1: gate preactivations ----------------
__global__ __launch_bounds__(256) void gate_kernel(
    const float* __restrict__ q, const float* __restrict__ k, const float* __restrict__ v,
    const float* __restrict__ Wi, const float* __restrict__ bi,
    const float* __restrict__ Wf, const float* __restrict__ bf,
    float* __restrict__ ipre, float* __restrict__ fpre)
{
  const int wave = threadIdx.x >> 6;
  const int lane = threadIdx.x & 63;
  const int pos  = blockIdx.x * 4 + wave;
  const int b = pos >> 11;
  const int s = pos & 2047;
  const float* qp = q + (size_t)pos * D_DIM;
  const float* kp = k + (size_t)pos * D_DIM;
  const float* vp = v + (size_t)pos * D_DIM;

  float acc[8] = {0.f,0.f,0.f,0.f,0.f,0.f,0.f,0.f};
  #pragma unroll
  for (int j = 0; j < 24; ++j) {
    int e = lane + (j << 6);
    float x;
    if (e < 512)       x = qp[e];
    else if (e < 1024) x = kp[e - 512];
    else               x = vp[e - 1024];
    #pragma unroll
    for (int h = 0; h < 4; ++h) {
      acc[h]     = fmaf(x, Wi[h * 1536 + e], acc[h]);
      acc[4 + h] = fmaf(x, Wf[h * 1536 + e], acc[4 + h]);
    }
  }
  #pragma unroll
  for (int off = 32; off > 0; off >>= 1) {
    #pragma unroll
    for (int a = 0; a < 8; ++a) acc[a] += __shfl_down(acc[a], off);
  }
  if (lane == 0) {
    #pragma unroll
    for (int h = 0; h < 4; ++h) {
      ipre[(size_t)(b * 4 + h) * S_LEN + s] = acc[h] + bi[h];
      fpre[(size_t)(b * 4 + h) * S_LEN + s] = acc[4 + h] + bf[h];
    }
  }
}

// ---------------- Kernel 2: single-pass register scans ----------------
__global__ __launch_bounds__(256) void scan_kernel(
    const float* __restrict__ ipre, const float* __restrict__ fpre,
    float* __restrict__ g_out, float* __restrict__ M_out,
    float* __restrict__ bsum_out, float* __restrict__ Gt_out)
{
  __shared__ float wsh[8];
  const int bh = blockIdx.x;
  const int tid = threadIdx.x, lane = tid & 63, wv = tid >> 6;
  const int base = tid * 8;
  const float* fp = fpre + (size_t)bh * S_LEN;
  const float* ip = ipre + (size_t)bh * S_LEN;

  float x[8], ls[8];
  float4 a0 = *(const float4*)(fp + base), a1 = *(const float4*)(fp + base + 4);
  x[0]=a0.x; x[1]=a0.y; x[2]=a0.z; x[3]=a0.w;
  x[4]=a1.x; x[5]=a1.y; x[6]=a1.z; x[7]=a1.w;
  float run = 0.f;
  #pragma unroll
  for (int i = 0; i < 8; ++i) {
    float lsv = fminf(x[i], 0.f) - log1pf(expf(-fabsf(x[i])));
    run += lsv; ls[i] = run;
  }
  float sc = run;
  #pragma unroll
  for (int off = 1; off < 64; off <<= 1) {
    float o = __shfl_up(sc, off);
    if (lane >= off) sc += o;
  }
  if (lane == 63) wsh[wv] = sc;
  __syncthreads();
  float woff = 0.f;
  #pragma unroll
  for (int u = 0; u < 4; ++u) if (u < wv) woff += wsh[u];
  const float ex = woff + (sc - run);

  float4 i0 = *(const float4*)(ip + base), i1 = *(const float4*)(ip + base + 4);
  float iv[8];
  iv[0]=i0.x; iv[1]=i0.y; iv[2]=i0.z; iv[3]=i0.w;
  iv[4]=i1.x; iv[5]=i1.y; iv[6]=i1.z; iv[7]=i1.w;
  float g[8], bc[8], pm[8];
  float runm = -3.0e38f;
  #pragma unroll
  for (int i = 0; i < 8; ++i) {
    bc[i] = ex + ls[i];
    g[i] = iv[i] - bc[i];
    runm = fmaxf(runm, g[i]);
    pm[i] = runm;
  }
  *(float4*)(bsum_out + (size_t)bh * S_LEN + base)     = make_float4(bc[0],bc[1],bc[2],bc[3]);
  *(float4*)(bsum_out + (size_t)bh * S_LEN + base + 4) = make_float4(bc[4],bc[5],bc[6],bc[7]);
  *(float4*)(g_out + (size_t)bh * S_LEN + base)        = make_float4(g[0],g[1],g[2],g[3]);
  *(float4*)(g_out + (size_t)bh * S_LEN + base + 4)    = make_float4(g[4],g[5],g[6],g[7]);

  float t8 = runm;
  t8 = fmaxf(t8, __shfl_xor(t8, 1));
  t8 = fmaxf(t8, __shfl_xor(t8, 2));
  t8 = fmaxf(t8, __shfl_xor(t8, 4));
  if ((tid & 7) == 0) Gt_out[bh * 32 + (tid >> 3)] = t8;

  float scm = runm;
  #pragma unroll
  for (int off = 1; off < 64; off <<= 1) {
    float o = __shfl_up(scm, off);
    if (lane >= off) scm = fmaxf(scm, o);
  }
  if (lane == 63) wsh[4 + wv] = scm;
  __syncthreads();
  float wmo = -3.0e38f;
  #pragma unroll
  for (int u = 0; u < 4; ++u) if (u < wv) wmo = fmaxf(wmo, wsh[4 + u]);
  float prev = __shfl_up(scm, 1);
  if (lane == 0) prev = -3.0e38f;
  const float exm = fmaxf(wmo, prev);
  float M[8];
  #pragma unroll
  for (int i = 0; i < 8; ++i) M[i] = fmaxf(exm, pm[i]);
  *(float4*)(M_out + (size_t)bh * S_LEN + base)     = make_float4(M[0],M[1],M[2],M[3]);
  *(float4*)(M_out + (size_t)bh * S_LEN + base + 4) = make_float4(M[4],M[5],M[6],M[7]);
}

// ---------------- Kernel 3: plain fp16 conversion ----------
// khat: global row s x 256B, elem d at byte (2d)^((s&15)<<4)
// vT tile (bh,jt64): row d(128) x 128B, elem s at byte (2s)^((d&15)<<3)
__global__ __launch_bounds__(256) void convert_kernel(
    const float* __restrict__ k, const float* __restrict__ v,
    char* __restrict__ khat, char* __restrict__ vT)
{
  const int it = blockIdx.x;     // 128-row tile index
  const int bh = blockIdx.y;
  const int b = bh >> 2, hh = bh & 3;
  const int tid = threadIdx.x;
  const size_t tb = (size_t)(bh * 16 + it) * 32768;
  const int rl = tid & 31, rg = tid >> 5;
  for (int j = 0; j < 16; ++j) {
    const int s = rg + 8 * j;
    const int sg = it * 128 + s;
    const float* krow = k + ((size_t)(b * S_LEN + sg)) * D_DIM + hh * DHEAD;
    float4 kv = *(const float4*)(krow + rl * 4);
    uint2 kp;
    kp.x = pkh(kv.x, kv.y);
    kp.y = pkh(kv.z, kv.w);
    const int off = (rl * 8) ^ ((s & 15) << 4);
    *(uint2*)(khat + tb + s * 256 + off) = kp;
  }
  const int d = tid & 127, oc = tid >> 7;
  const int swz8 = (d & 15) << 3;
  #pragma unroll
  for (int jt = 0; jt < 2; ++jt) {
    const size_t vtb = (size_t)(bh * 32 + it * 2 + jt) * 16384 + (size_t)d * 128;
    for (int j = 0; j < 4; ++j) {
      const int s0 = (oc + 2 * j) * 8;
      float vv[8];
      #pragma unroll
      for (int i = 0; i < 8; ++i)
        vv[i] = v[((size_t)(b * S_LEN + it * 128 + jt * 64 + s0 + i)) * D_DIM + hh * DHEAD + d];
      uint2 p0, p1;
      p0.x = pkh(vv[0], vv[1]); p0.y = pkh(vv[2], vv[3]);
      p1.x = pkh(vv[4], vv[5]); p1.y = pkh(vv[6], vv[7]);
      *(uint2*)(vT + vtb + ((2 * s0) ^ swz8))     = p0;
      *(uint2*)(vT + vtb + ((2 * s0 + 8) ^ swz8)) = p1;
    }
  }
}

// ---------------- Kernel 4: balanced MFMA attention, 2 blocks/CU ----------------
// 32-row q-tiles j in 0..63; block (bh,p) processes pair (63-p, p): uniform work.
// grid (16,32) bh-major -> flat%8 == bh%8 (XCD-local K/V stream, L2-served).
// 4 waves: sh = s-half of 64-col kt tile, dh = d-half for PV (QK dup across dh).
// Decay: cf=exp(g[s]-Gt) on K A-frag; rf=exp(Gt-Mt) post-MFMA. Dual QK accums.
__global__ __launch_bounds__(256, 2) void attn_kernel(
    const float* __restrict__ q, const char* __restrict__ khat, const char* __restrict__ vT,
    const float* __restrict__ g_arr, const float* __restrict__ M_arr,
    const float* __restrict__ bs_arr, const float* __restrict__ Gt_arr,
    const float* __restrict__ ln_w, const float* __restrict__ ln_b,
    float* __restrict__ out)
{
  __shared__ __align__(16) char smem[65536];   // buf c at c*32768: K 16K + V 16K
  const int bh = blockIdx.x;
  const int p  = blockIdx.y;          // 0..31
  const int b = bh >> 2, hh = bh & 3;
  const int tid = threadIdx.x;
  const int w = tid >> 6, lane = tid & 63, lo = lane & 31, hi = lane >> 5;
  const int sh = w & 1, dh = w >> 1;
  const int swz = (lo & 15) << 4;

  const char* gk = khat + (size_t)bh * 524288;
  const char* gv = vT   + (size_t)bh * 524288;
  const float* Mb  = M_arr  + (size_t)bh * S_LEN;
  const float* bsb = bs_arr + (size_t)bh * S_LEN;
  const float* gb  = g_arr  + (size_t)bh * S_LEN;
  const float* Gtb = Gt_arr + bh * 32;

  for (int half = 0; half < 2; ++half) {
    const int j  = half ? p : (63 - p);
    const int tg = 32 * j + lo;
    const float Mt = Mb[tg];
    const float em = __expf(-(bsb[tg] + Mt));
    const float M0 = Mb[32 * j];
    const int ktLast = (32 * j + 31) >> 6;
    int kts = 0;
    while (kts < ktLast && Gtb[kts] < M0 - 25.f) ++kts;

    // Q fragments straight from fp32 global (once per tile)
    f16x8 qf[8];
    const float* qrow = q + ((size_t)(b * S_LEN + tg)) * D_DIM + hh * DHEAD;
    #pragma unroll
    for (int ks = 0; ks < 8; ++ks) {
      const int d0 = ks * 16 + hi * 8;
      float4 x0 = *(const float4*)(qrow + d0);
      float4 x1 = *(const float4*)(qrow + d0 + 4);
      uint4 u;
      u.x = pkh(x0.x * SCALE_QK, x0.y * SCALE_QK);
      u.y = pkh(x0.z * SCALE_QK, x0.w * SCALE_QK);
      u.z = pkh(x1.x * SCALE_QK, x1.y * SCALE_QK);
      u.w = pkh(x1.z * SCALE_QK, x1.w * SCALE_QK);
      qf[ks] = __builtin_bit_cast(f16x8, u);
    }

    __syncthreads();   // prev epilogue LDS reads done before restaging
    {
      const char* gkt = gk + (size_t)kts * 16384;
      const char* gvt = gv + (size_t)kts * 16384;
      #pragma unroll
      for (int i = 0; i < 4; ++i) {
        int off = (i * 256 + tid) * 16;
        __builtin_amdgcn_global_load_lds((const AS1 void*)(gkt + off), (AS3 void*)(smem + off), 16, 0, 0);
        __builtin_amdgcn_global_load_lds((const AS1 void*)(gvt + off), (AS3 void*)(smem + 16384 + off), 16, 0, 0);
      }
    }
    asm volatile("s_waitcnt vmcnt(0)" ::: "memory");
    __syncthreads();

    f32x16 h0 = {}, h1 = {};
    float rowsum = 0.f;
    int cur = 0;
    for (int kt = kts; kt <= ktLast; ++kt) {
      if (kt < ktLast) {
        char* lb = smem + (cur ^ 1) * 32768;
        const char* gkt = gk + (size_t)(kt + 1) * 16384;
        const char* gvt = gv + (size_t)(kt + 1) * 16384;
        #pragma unroll
        for (int i = 0; i < 4; ++i) {
          int off = (i * 256 + tid) * 16;
          __builtin_amdgcn_global_load_lds((const AS1 void*)(gkt + off), (AS3 void*)(lb + off), 16, 0, 0);
          __builtin_amdgcn_global_load_lds((const AS1 void*)(gvt + off), (AS3 void*)(lb + 16384 + off), 16, 0, 0);
        }
      }
      const float Gtv = Gtb[kt];
      const float dM = Gtv - Mt;
      if (__any(dM >= -25.f)) {
        const float rf = __expf(dM);
        const char* kb  = smem + cur * 32768;
        const char* vbp = kb + 16384;
        const float cf = __expf(gb[64 * kt + 32 * sh + lo] - Gtv);
        const _Float16 cfh = (_Float16)cf;
        // QK^T (dup across dh), dual accumulators to halve the MFMA chain
        f32x16 sacc0 = {}, sacc1 = {};
        const char* krow = kb + (32 * sh + lo) * 256;
        #pragma unroll
        for (int ks = 0; ks < 4; ++ks) {
          f16x8 a0v = *(const f16x8*)(krow + (((2 * ks) * 32 + hi * 16) ^ swz));
          f16x8 a1v = *(const f16x8*)(krow + (((2 * ks + 1) * 32 + hi * 16) ^ swz));
          a0v = a0v * cfh;
          a1v = a1v * cfh;
          sacc0 = __builtin_amdgcn_mfma_f32_32x32x16_f16(a0v, qf[2 * ks], sacc0, 0, 0, 0);
          sacc1 = __builtin_amdgcn_mfma_f32_32x32x16_f16(a1v, qf[2 * ks + 1], sacc1, 0, 0, 0);
        }
        const int bnd = 32 * j + lo - 64 * kt;   // mask s-local > bnd
        float vals[16];
        float tsum = 0.f;
        #pragma unroll
        for (int r = 0; r < 16; ++r) {
          float val = (sacc0[r] + sacc1[r]) * rf;
          int sl = 32 * sh + (r & 3) + 8 * (r >> 2) + 4 * hi;
          if (sl > bnd) val = 0.f;
          tsum += val;
          vals[r] = val;
        }
        rowsum += tsum + __shfl_xor(tsum, 32);
        uint32_t a0 = pkh(vals[0], vals[1]),   a1 = pkh(vals[2], vals[3]);
        uint32_t a2 = pkh(vals[4], vals[5]),   a3 = pkh(vals[6], vals[7]);
        uint32_t b0 = pkh(vals[8], vals[9]),   b1 = pkh(vals[10], vals[11]);
        uint32_t b2 = pkh(vals[12], vals[13]), b3 = pkh(vals[14], vals[15]);
        uint32_t sa0 = __shfl_xor(a0, 32), sa1 = __shfl_xor(a1, 32);
        uint32_t sa2 = __shfl_xor(a2, 32), sa3 = __shfl_xor(a3, 32);
        uint32_t sb0 = __shfl_xor(b0, 32), sb1 = __shfl_xor(b1, 32);
        uint32_t sb2 = __shfl_xor(b2, 32), sb3 = __shfl_xor(b3, 32);
        uint4 f0, f1;
        f0.x = hi ? sa2 : a0;  f0.y = hi ? sa3 : a1;
        f0.z = hi ? a2 : sa0;  f0.w = hi ? a3 : sa1;
        f1.x = hi ? sb2 : b0;  f1.y = hi ? sb3 : b1;
        f1.z = hi ? b2 : sb0;  f1.w = hi ? b3 : sb1;
        // PV: this wave's d-half (2 blocks of 32) over its s-half
        #pragma unroll
        for (int dfi = 0; dfi < 2; ++dfi) {
          const int d = 64 * dh + 32 * dfi + lo;
          const char* vrow = vbp + d * 128;
          const int swzv = (d & 15) << 3;
          #pragma unroll
          for (int ks2 = 0; ks2 < 2; ++ks2) {
            const int xx = sh * 64 + ks2 * 32 + hi * 16;
            uint2 p0 = *(const uint2*)(vrow + (xx ^ swzv));
            uint2 p1 = *(const uint2*)(vrow + ((xx + 8) ^ swzv));
            uint4 av; av.x = p0.x; av.y = p0.y; av.z = p1.x; av.w = p1.y;
            f16x8 a = __builtin_bit_cast(f16x8, av);
            f16x8 pp = __builtin_bit_cast(f16x8, ks2 ? f1 : f0);
            if (dfi) h1 = __builtin_amdgcn_mfma_f32_32x32x16_f16(a, pp, h1, 0, 0, 0);
            else     h0 = __builtin_amdgcn_mfma_f32_32x32x16_f16(a, pp, h0, 0, 0, 0);
          }
        }
      }
      asm volatile("s_waitcnt vmcnt(0)" ::: "memory");
      __syncthreads();
      cur ^= 1;
    }

    // ---- combine s-halves + epilogue ----
    float* cb = (float*)smem;
    if (sh == 1) {
      #pragma unroll
      for (int r = 0; r < 16; ++r) {
        cb[(dh * 2 + 0) * 1024 + r * 64 + lane] = h0[r];
        cb[(dh * 2 + 1) * 1024 + r * 64 + lane] = h1[r];
      }
      if (dh == 0) cb[4096 + lane] = rowsum;
    }
    __syncthreads();
    float s1 = 0.f, s2 = 0.f;
    if (sh == 0) {
      #pragma unroll
      for (int r = 0; r < 16; ++r) {
        h0[r] += cb[(dh * 2 + 0) * 1024 + r * 64 + lane];
        h1[r] += cb[(dh * 2 + 1) * 1024 + r * 64 + lane];
      }
      rowsum += cb[4096 + lane];
      float n = fmaxf(fabsf(rowsum), em);
      float invn = 1.f / (n + 5e-5f);
      #pragma unroll
      for (int r = 0; r < 16; ++r) {
        float x0 = h0[r] * invn, x1 = h1[r] * invn;
        h0[r] = x0; h1[r] = x1;
        s1 += x0 + x1; s2 += x0 * x0 + x1 * x1;
      }
      s1 += __shfl_xor(s1, 32);
      s2 += __shfl_xor(s2, 32);
      cb[4160 + dh * 64 + lane] = s1;
      cb[4288 + dh * 64 + lane] = s2;
    }
    __syncthreads();
    if (sh == 0) {
      s1 += cb[4160 + (dh ^ 1) * 64 + lane];
      s2 += cb[4288 + (dh ^ 1) * 64 + lane];
      float mu = s1 * (1.f / 128.f);
      float var = s2 * (1.f / 128.f) - mu * mu;
      float rstd = rsqrtf(var + 1e-3f);
      float* orow = out + ((size_t)(b * S_LEN) + tg) * D_DIM + hh * DHEAD;
      #pragma unroll
      for (int dfi = 0; dfi < 2; ++dfi) {
        #pragma unroll
        for (int rq = 0; rq < 4; ++rq) {
          int dbase = 64 * dh + 32 * dfi + 8 * rq + 4 * hi;
          float4 wv = *(const float4*)(ln_w + hh * DHEAD + dbase);
          float4 bv = *(const float4*)(ln_b + hh * DHEAD + dbase);
          float v0 = dfi ? h1[rq * 4 + 0] : h0[rq * 4 + 0];
          float v1 = dfi ? h1[rq * 4 + 1] : h0[rq * 4 + 1];
          float v2 = dfi ? h1[rq * 4 + 2] : h0[rq * 4 + 2];
          float v3 = dfi ? h1[rq * 4 + 3] : h0[rq * 4 + 3];
          float4 o;
          o.x = (v0 - mu) * rstd * (1.f + wv.x) + bv.x;
          o.y = (v1 - mu) * rstd * (1.f + wv.y) + bv.y;
          o.z = (v2 - mu) * rstd * (1.f + wv.z) + bv.z;
          o.w = (v3 - mu) * rstd * (1.f + wv.w) + bv.w;
          *(float4*)(orow + dbase) = o;
        }
      }
    }
    __syncthreads();   // cb region reused as staging buffer next half
  }
}

extern "C" void kernel_launch(void* const* d_in, const int* in_sizes, int n_in,
                              void* d_out, int out_size, void* d_ws, size_t ws_size,
                              hipStream_t stream) {
  (void)in_sizes; (void)n_in; (void)out_size; (void)ws_size;
  const float* q    = (const float*)d_in[0];
  const float* k    = (const float*)d_in[1];
  const float* v    = (const float*)d_in[2];
  const float* Wi   = (const float*)d_in[3];
  const float* bi   = (const float*)d_in[4];
  const float* Wf   = (const float*)d_in[5];
  const float* bf   = (const float*)d_in[6];
  const float* ln_w = (const float*)d_in[7];
  const float* ln_b = (const float*)d_in[8];

  char* wsb = (char*)d_ws;
  float* ipre = (float*)(wsb + 0);
  float* fpre = (float*)(wsb + 131072);
  float* garr = (float*)(wsb + 262144);
  float* Marr = (float*)(wsb + 393216);
  float* bsum = (float*)(wsb + 524288);
  float* Gt   = (float*)(wsb + 655360);       // 16*32 floats
  char* kh = wsb + 1048576;
  char* vt = wsb + 1048576 + 8388608;

  gate_kernel<<<2048, 256, 0, stream>>>(q, k, v, Wi, bi, Wf, bf, ipre, fpre);
  scan_kernel<<<16, 256, 0, stream>>>(ipre, fpre, garr, Marr, bsum, Gt);
  convert_kernel<<<dim3(16, 16), 256, 0, stream>>>(k, v, kh, vt);
  attn_kernel<<<dim3(16, 32), 256, 0, stream>>>(q, kh, vt, garr, Marr, bsum, Gt,
                                                ln_w, ln_b, (float*)d_out);
}

// Round 8
// 95.748 us; speedup vs baseline: 1.0441x; 1.0441x over previous
//
#include <hip/hip_runtime.h>
#include <cstddef>
#include <cstdint>

#define S_LEN 2048
#define D_DIM 512
#define NHEAD 4
#define DHEAD 128
#define BH_CNT 16
#define SCALE_QK 0.08838834764831845f

typedef _Float16 f16;
typedef _Float16 f16x8 __attribute__((ext_vector_type(8)));
typedef float f32x16 __attribute__((ext_vector_type(16)));

#define AS1 __attribute__((address_space(1)))
#define AS3 __attribute__((address_space(3)))

__device__ __forceinline__ unsigned pkh(float a, float b) {
  auto r = __builtin_amdgcn_cvt_pkrtz(a, b);   // __fp16 ext_vector_type(2)
  return __builtin_bit_cast(unsigned, r);
}

// ---------------- Kernel 1: gate preactivations ----------------
__global__ __launch_bounds__(256) void gate_kernel(
    const float* __restrict__ q, const float* __restrict__ k, const float* __restrict__ v,
    const float* __restrict__ Wi, const float* __restrict__ bi,
    const float* __restrict__ Wf, const float* __restrict__ bf,
    float* __restrict__ ipre, float* __restrict__ fpre)
{
  const int wave = threadIdx.x >> 6;
  const int lane = threadIdx.x & 63;
  const int pos  = blockIdx.x * 4 + wave;
  const int b = pos >> 11;
  const int s = pos & 2047;
  const float* qp = q + (size_t)pos * D_DIM;
  const float* kp = k + (size_t)pos * D_DIM;
  const float* vp = v + (size_t)pos * D_DIM;

  float acc[8] = {0.f,0.f,0.f,0.f,0.f,0.f,0.f,0.f};
  #pragma unroll
  for (int j = 0; j < 24; ++j) {
    int e = lane + (j << 6);
    float x;
    if (e < 512)       x = qp[e];
    else if (e < 1024) x = kp[e - 512];
    else               x = vp[e - 1024];
    #pragma unroll
    for (int h = 0; h < 4; ++h) {
      acc[h]     = fmaf(x, Wi[h * 1536 + e], acc[h]);
      acc[4 + h] = fmaf(x, Wf[h * 1536 + e], acc[4 + h]);
    }
  }
  #pragma unroll
  for (int off = 32; off > 0; off >>= 1) {
    #pragma unroll
    for (int a = 0; a < 8; ++a) acc[a] += __shfl_down(acc[a], off);
  }
  if (lane == 0) {
    #pragma unroll
    for (int h = 0; h < 4; ++h) {
      ipre[(size_t)(b * 4 + h) * S_LEN + s] = acc[h] + bi[h];
      fpre[(size_t)(b * 4 + h) * S_LEN + s] = acc[4 + h] + bf[h];
    }
  }
}

// ---------------- Kernel 2: single-pass register scans ----------------
__global__ __launch_bounds__(256) void scan_kernel(
    const float* __restrict__ ipre, const float* __restrict__ fpre,
    float* __restrict__ g_out, float* __restrict__ M_out,
    float* __restrict__ bsum_out, float* __restrict__ Gt_out)
{
  __shared__ float wsh[8];
  const int bh = blockIdx.x;
  const int tid = threadIdx.x, lane = tid & 63, wv = tid >> 6;
  const int base = tid * 8;
  const float* fp = fpre + (size_t)bh * S_LEN;
  const float* ip = ipre + (size_t)bh * S_LEN;

  float x[8], ls[8];
  float4 a0 = *(const float4*)(fp + base), a1 = *(const float4*)(fp + base + 4);
  x[0]=a0.x; x[1]=a0.y; x[2]=a0.z; x[3]=a0.w;
  x[4]=a1.x; x[5]=a1.y; x[6]=a1.z; x[7]=a1.w;
  float run = 0.f;
  #pragma unroll
  for (int i = 0; i < 8; ++i) {
    float lsv = fminf(x[i], 0.f) - log1pf(expf(-fabsf(x[i])));
    run += lsv; ls[i] = run;
  }
  float sc = run;
  #pragma unroll
  for (int off = 1; off < 64; off <<= 1) {
    float o = __shfl_up(sc, off);
    if (lane >= off) sc += o;
  }
  if (lane == 63) wsh[wv] = sc;
  __syncthreads();
  float woff = 0.f;
  #pragma unroll
  for (int u = 0; u < 4; ++u) if (u < wv) woff += wsh[u];
  const float ex = woff + (sc - run);

  float4 i0 = *(const float4*)(ip + base), i1 = *(const float4*)(ip + base + 4);
  float iv[8];
  iv[0]=i0.x; iv[1]=i0.y; iv[2]=i0.z; iv[3]=i0.w;
  iv[4]=i1.x; iv[5]=i1.y; iv[6]=i1.z; iv[7]=i1.w;
  float g[8], bc[8], pm[8];
  float runm = -3.0e38f;
  #pragma unroll
  for (int i = 0; i < 8; ++i) {
    bc[i] = ex + ls[i];
    g[i] = iv[i] - bc[i];
    runm = fmaxf(runm, g[i]);
    pm[i] = runm;
  }
  *(float4*)(bsum_out + (size_t)bh * S_LEN + base)     = make_float4(bc[0],bc[1],bc[2],bc[3]);
  *(float4*)(bsum_out + (size_t)bh * S_LEN + base + 4) = make_float4(bc[4],bc[5],bc[6],bc[7]);
  *(float4*)(g_out + (size_t)bh * S_LEN + base)        = make_float4(g[0],g[1],g[2],g[3]);
  *(float4*)(g_out + (size_t)bh * S_LEN + base + 4)    = make_float4(g[4],g[5],g[6],g[7]);

  float t8 = runm;
  t8 = fmaxf(t8, __shfl_xor(t8, 1));
  t8 = fmaxf(t8, __shfl_xor(t8, 2));
  t8 = fmaxf(t8, __shfl_xor(t8, 4));
  if ((tid & 7) == 0) Gt_out[bh * 32 + (tid >> 3)] = t8;

  float scm = runm;
  #pragma unroll
  for (int off = 1; off < 64; off <<= 1) {
    float o = __shfl_up(scm, off);
    if (lane >= off) scm = fmaxf(scm, o);
  }
  if (lane == 63) wsh[4 + wv] = scm;
  __syncthreads();
  float wmo = -3.0e38f;
  #pragma unroll
  for (int u = 0; u < 4; ++u) if (u < wv) wmo = fmaxf(wmo, wsh[4 + u]);
  float prev = __shfl_up(scm, 1);
  if (lane == 0) prev = -3.0e38f;
  const float exm = fmaxf(wmo, prev);
  float M[8];
  #pragma unroll
  for (int i = 0; i < 8; ++i) M[i] = fmaxf(exm, pm[i]);
  *(float4*)(M_out + (size_t)bh * S_LEN + base)     = make_float4(M[0],M[1],M[2],M[3]);
  *(float4*)(M_out + (size_t)bh * S_LEN + base + 4) = make_float4(M[4],M[5],M[6],M[7]);
}

// ---------------- Kernel 3: fp16 conversion, decay folded into khat ----------
// khat: global row s x 256B, elem d at byte (2d)^((s&15)<<4), value k*exp(g-Gt64)
// vT tile (bh,jt64): row d(128) x 128B, elem s at byte (2s)^((d&15)<<3)
__global__ __launch_bounds__(256) void convert_kernel(
    const float* __restrict__ k, const float* __restrict__ v,
    const float* __restrict__ g_arr, const float* __restrict__ Gt_arr,
    char* __restrict__ khat, char* __restrict__ vT)
{
  const int it = blockIdx.x;     // 128-row tile index
  const int bh = blockIdx.y;
  const int b = bh >> 2, hh = bh & 3;
  const int tid = threadIdx.x;
  const size_t tb = (size_t)(bh * 16 + it) * 32768;
  const int rl = tid & 31, rg = tid >> 5;
  for (int j = 0; j < 16; ++j) {
    const int s = rg + 8 * j;
    const int sg = it * 128 + s;
    const float* krow = k + ((size_t)(b * S_LEN + sg)) * D_DIM + hh * DHEAD;
    float4 kv = *(const float4*)(krow + rl * 4);
    const float cf = __expf(g_arr[(size_t)bh * S_LEN + sg] - Gt_arr[bh * 32 + (sg >> 6)]);
    uint2 kp;
    kp.x = pkh(kv.x * cf, kv.y * cf);
    kp.y = pkh(kv.z * cf, kv.w * cf);
    const int off = (rl * 8) ^ ((s & 15) << 4);
    *(uint2*)(khat + tb + s * 256 + off) = kp;
  }
  const int d = tid & 127, oc = tid >> 7;
  const int swz8 = (d & 15) << 3;
  #pragma unroll
  for (int jt = 0; jt < 2; ++jt) {
    const size_t vtb = (size_t)(bh * 32 + it * 2 + jt) * 16384 + (size_t)d * 128;
    for (int j = 0; j < 4; ++j) {
      const int s0 = (oc + 2 * j) * 8;
      float vv[8];
      #pragma unroll
      for (int i = 0; i < 8; ++i)
        vv[i] = v[((size_t)(b * S_LEN + it * 128 + jt * 64 + s0 + i)) * D_DIM + hh * DHEAD + d];
      uint2 p0, p1;
      p0.x = pkh(vv[0], vv[1]); p0.y = pkh(vv[2], vv[3]);
      p1.x = pkh(vv[4], vv[5]); p1.y = pkh(vv[6], vv[7]);
      *(uint2*)(vT + vtb + ((2 * s0) ^ swz8))     = p0;
      *(uint2*)(vT + vtb + ((2 * s0 + 8) ^ swz8)) = p1;
    }
  }
}

__device__ __forceinline__ void stage_tile(char* lds, const char* gk, const char* gv,
                                           int kt, int tid) {
  const char* gkt = gk + (size_t)kt * 16384;
  const char* gvt = gv + (size_t)kt * 16384;
  #pragma unroll
  for (int i = 0; i < 4; ++i) {
    int off = (i * 256 + tid) * 16;
    __builtin_amdgcn_global_load_lds((const AS1 void*)(gkt + off), (AS3 void*)(lds + off), 16, 0, 0);
    __builtin_amdgcn_global_load_lds((const AS1 void*)(gvt + off), (AS3 void*)(lds + 16384 + off), 16, 0, 0);
  }
}

// ---------------- Kernel 4: pipelined MFMA attention (counted vmcnt) ---------
// 32-row q-tiles j in 0..63; block (bh,p) processes pair (63-p, p): uniform work.
// grid (16,32) bh-major -> flat%8 == bh%8 (XCD-local K/V stream, L2-served).
// 4 waves: sh = s-half of 64-col kt tile, dh = d-half for PV (QK dup across dh).
// 2-deep staging pipeline: loop top waits vmcnt(8) (next tile stays in flight),
// raw s_barrier; stage kt+2 after lgkmcnt(0)+barrier. No vmcnt(0) drain in loop.
__global__ __launch_bounds__(256, 2) void attn_kernel(
    const float* __restrict__ q, const char* __restrict__ khat, const char* __restrict__ vT,
    const float* __restrict__ M_arr, const float* __restrict__ bs_arr,
    const float* __restrict__ Gt_arr,
    const float* __restrict__ ln_w, const float* __restrict__ ln_b,
    float* __restrict__ out)
{
  __shared__ __align__(16) char smem[65536];   // buf c at c*32768: K 16K + V 16K
  const int bh = blockIdx.x;
  const int p  = blockIdx.y;          // 0..31
  const int b = bh >> 2, hh = bh & 3;
  const int tid = threadIdx.x;
  const int w = tid >> 6, lane = tid & 63, lo = lane & 31, hi = lane >> 5;
  const int sh = w & 1, dh = w >> 1;
  const int swz = (lo & 15) << 4;

  const char* gk = khat + (size_t)bh * 524288;
  const char* gv = vT   + (size_t)bh * 524288;
  const float* Mb  = M_arr  + (size_t)bh * S_LEN;
  const float* bsb = bs_arr + (size_t)bh * S_LEN;
  const float* Gtb = Gt_arr + bh * 32;

  const float GtReg = Gtb[lo];        // lane i holds Gt[i] (i<32; dup for hi)

  for (int half = 0; half < 2; ++half) {
    const int j  = half ? p : (63 - p);
    const int tg = 32 * j + lo;
    const float Mt = Mb[tg];
    const float em = __expf(-(bsb[tg] + Mt));
    const float M0 = Mb[32 * j];
    const int ktLast = (32 * j + 31) >> 6;
    int kts = 0;
    while (kts < ktLast && Gtb[kts] < M0 - 25.f) ++kts;

    // Q fragments straight from fp32 global (once per tile)
    f16x8 qf[8];
    const float* qrow = q + ((size_t)(b * S_LEN + tg)) * D_DIM + hh * DHEAD;
    #pragma unroll
    for (int ks = 0; ks < 8; ++ks) {
      const int d0 = ks * 16 + hi * 8;
      float4 x0 = *(const float4*)(qrow + d0);
      float4 x1 = *(const float4*)(qrow + d0 + 4);
      uint4 u;
      u.x = pkh(x0.x * SCALE_QK, x0.y * SCALE_QK);
      u.y = pkh(x0.z * SCALE_QK, x0.w * SCALE_QK);
      u.z = pkh(x1.x * SCALE_QK, x1.y * SCALE_QK);
      u.w = pkh(x1.z * SCALE_QK, x1.w * SCALE_QK);
      qf[ks] = __builtin_bit_cast(f16x8, u);
    }

    __syncthreads();   // prev epilogue LDS reads done before restaging
    stage_tile(smem, gk, gv, kts, tid);
    if (kts + 1 <= ktLast) stage_tile(smem + 32768, gk, gv, kts + 1, tid);

    f32x16 h0 = {}, h1 = {};
    float rowsum = 0.f;
    int cur = 0;
    for (int kt = kts; kt <= ktLast; ++kt) {
      if (kt < ktLast) { asm volatile("s_waitcnt vmcnt(8)" ::: "memory"); }
      else             { asm volatile("s_waitcnt vmcnt(0)" ::: "memory"); }
      __builtin_amdgcn_sched_barrier(0);
      __builtin_amdgcn_s_barrier();

      const float Gtv = __shfl(GtReg, kt);
      const float dM = Gtv - Mt;
      if (__any(dM >= -25.f)) {
        const float rf = __expf(dM);
        const char* kb  = smem + cur * 32768;
        const char* vbp = kb + 16384;
        // QK^T (dup across dh), dual accumulators to halve the MFMA chain
        f32x16 sacc0 = {}, sacc1 = {};
        const char* krow = kb + (32 * sh + lo) * 256;
        #pragma unroll
        for (int ks = 0; ks < 4; ++ks) {
          f16x8 a0v = *(const f16x8*)(krow + (((2 * ks) * 32 + hi * 16) ^ swz));
          f16x8 a1v = *(const f16x8*)(krow + (((2 * ks + 1) * 32 + hi * 16) ^ swz));
          sacc0 = __builtin_amdgcn_mfma_f32_32x32x16_f16(a0v, qf[2 * ks], sacc0, 0, 0, 0);
          sacc1 = __builtin_amdgcn_mfma_f32_32x32x16_f16(a1v, qf[2 * ks + 1], sacc1, 0, 0, 0);
        }
        const int bnd = 32 * j + lo - 64 * kt;   // mask s-local > bnd
        float vals[16];
        float tsum = 0.f;
        #pragma unroll
        for (int r = 0; r < 16; ++r) {
          float val = (sacc0[r] + sacc1[r]) * rf;
          int sl = 32 * sh + (r & 3) + 8 * (r >> 2) + 4 * hi;
          if (sl > bnd) val = 0.f;
          tsum += val;
          vals[r] = val;
        }
        rowsum += tsum + __shfl_xor(tsum, 32);
        uint32_t a0 = pkh(vals[0], vals[1]),   a1 = pkh(vals[2], vals[3]);
        uint32_t a2 = pkh(vals[4], vals[5]),   a3 = pkh(vals[6], vals[7]);
        uint32_t b0 = pkh(vals[8], vals[9]),   b1 = pkh(vals[10], vals[11]);
        uint32_t b2 = pkh(vals[12], vals[13]), b3 = pkh(vals[14], vals[15]);
        uint32_t sa0 = __shfl_xor(a0, 32), sa1 = __shfl_xor(a1, 32);
        uint32_t sa2 = __shfl_xor(a2, 32), sa3 = __shfl_xor(a3, 32);
        uint32_t sb0 = __shfl_xor(b0, 32), sb1 = __shfl_xor(b1, 32);
        uint32_t sb2 = __shfl_xor(b2, 32), sb3 = __shfl_xor(b3, 32);
        uint4 f0, f1;
        f0.x = hi ? sa2 : a0;  f0.y = hi ? sa3 : a1;
        f0.z = hi ? a2 : sa0;  f0.w = hi ? a3 : sa1;
        f1.x = hi ? sb2 : b0;  f1.y = hi ? sb3 : b1;
        f1.z = hi ? b2 : sb0;  f1.w = hi ? b3 : sb1;
        // PV: this wave's d-half (2 blocks of 32) over its s-half
        #pragma unroll
        for (int dfi = 0; dfi < 2; ++dfi) {
          const int d = 64 * dh + 32 * dfi + lo;
          const char* vrow = vbp + d * 128;
          const int swzv = (d & 15) << 3;
          #pragma unroll
          for (int ks2 = 0; ks2 < 2; ++ks2) {
            const int xx = sh * 64 + ks2 * 32 + hi * 16;
            uint2 p0 = *(const uint2*)(vrow + (xx ^ swzv));
            uint2 p1 = *(const uint2*)(vrow + ((xx + 8) ^ swzv));
            uint4 av; av.x = p0.x; av.y = p0.y; av.z = p1.x; av.w = p1.y;
            f16x8 a = __builtin_bit_cast(f16x8, av);
            f16x8 pp = __builtin_bit_cast(f16x8, ks2 ? f1 : f0);
            if (dfi) h1 = __builtin_amdgcn_mfma_f32_32x32x16_f16(a, pp, h1, 0, 0, 0);
            else     h0 = __builtin_amdgcn_mfma_f32_32x32x16_f16(a, pp, h0, 0, 0, 0);
          }
        }
      }
      asm volatile("s_waitcnt lgkmcnt(0)" ::: "memory");
      __builtin_amdgcn_sched_barrier(0);
      __builtin_amdgcn_s_barrier();
      if (kt + 2 <= ktLast) stage_tile(smem + cur * 32768, gk, gv, kt + 2, tid);
      cur ^= 1;
    }

    // ---- combine s-halves + epilogue ----
    float* cb = (float*)smem;
    if (sh == 1) {
      #pragma unroll
      for (int r = 0; r < 16; ++r) {
        cb[(dh * 2 + 0) * 1024 + r * 64 + lane] = h0[r];
        cb[(dh * 2 + 1) * 1024 + r * 64 + lane] = h1[r];
      }
      if (dh == 0) cb[4096 + lane] = rowsum;
    }
    __syncthreads();
    float s1 = 0.f, s2 = 0.f;
    if (sh == 0) {
      #pragma unroll
      for (int r = 0; r < 16; ++r) {
        h0[r] += cb[(dh * 2 + 0) * 1024 + r * 64 + lane];
        h1[r] += cb[(dh * 2 + 1) * 1024 + r * 64 + lane];
      }
      rowsum += cb[4096 + lane];
      float n = fmaxf(fabsf(rowsum), em);
      float invn = 1.f / (n + 5e-5f);
      #pragma unroll
      for (int r = 0; r < 16; ++r) {
        float x0 = h0[r] * invn, x1 = h1[r] * invn;
        h0[r] = x0; h1[r] = x1;
        s1 += x0 + x1; s2 += x0 * x0 + x1 * x1;
      }
      s1 += __shfl_xor(s1, 32);
      s2 += __shfl_xor(s2, 32);
      cb[4160 + dh * 64 + lane] = s1;
      cb[4288 + dh * 64 + lane] = s2;
    }
    __syncthreads();
    if (sh == 0) {
      s1 += cb[4160 + (dh ^ 1) * 64 + lane];
      s2 += cb[4288 + (dh ^ 1) * 64 + lane];
      float mu = s1 * (1.f / 128.f);
      float var = s2 * (1.f / 128.f) - mu * mu;
      float rstd = rsqrtf(var + 1e-3f);
      float* orow = out + ((size_t)(b * S_LEN) + tg) * D_DIM + hh * DHEAD;
      #pragma unroll
      for (int dfi = 0; dfi < 2; ++dfi) {
        #pragma unroll
        for (int rq = 0; rq < 4; ++rq) {
          int dbase = 64 * dh + 32 * dfi + 8 * rq + 4 * hi;
          float4 wv = *(const float4*)(ln_w + hh * DHEAD + dbase);
          float4 bv = *(const float4*)(ln_b + hh * DHEAD + dbase);
          float v0 = dfi ? h1[rq * 4 + 0] : h0[rq * 4 + 0];
          float v1 = dfi ? h1[rq * 4 + 1] : h0[rq * 4 + 1];
          float v2 = dfi ? h1[rq * 4 + 2] : h0[rq * 4 + 2];
          float v3 = dfi ? h1[rq * 4 + 3] : h0[rq * 4 + 3];
          float4 o;
          o.x = (v0 - mu) * rstd * (1.f + wv.x) + bv.x;
          o.y = (v1 - mu) * rstd * (1.f + wv.y) + bv.y;
          o.z = (v2 - mu) * rstd * (1.f + wv.z) + bv.z;
          o.w = (v3 - mu) * rstd * (1.f + wv.w) + bv.w;
          *(float4*)(orow + dbase) = o;
        }
      }
    }
    __syncthreads();   // cb region reused as staging buffer next half
  }
}

extern "C" void kernel_launch(void* const* d_in, const int* in_sizes, int n_in,
                              void* d_out, int out_size, void* d_ws, size_t ws_size,
                              hipStream_t stream) {
  (void)in_sizes; (void)n_in; (void)out_size; (void)ws_size;
  const float* q    = (const float*)d_in[0];
  const float* k    = (const float*)d_in[1];
  const float* v    = (const float*)d_in[2];
  const float* Wi   = (const float*)d_in[3];
  const float* bi   = (const float*)d_in[4];
  const float* Wf   = (const float*)d_in[5];
  const float* bf   = (const float*)d_in[6];
  const float* ln_w = (const float*)d_in[7];
  const float* ln_b = (const float*)d_in[8];

  char* wsb = (char*)d_ws;
  float* ipre = (float*)(wsb + 0);
  float* fpre = (float*)(wsb + 131072);
  float* garr = (float*)(wsb + 262144);
  float* Marr = (float*)(wsb + 393216);
  float* bsum = (float*)(wsb + 524288);
  float* Gt   = (float*)(wsb + 655360);       // 16*32 floats
  char* kh = wsb + 1048576;
  char* vt = wsb + 1048576 + 8388608;

  gate_kernel<<<2048, 256, 0, stream>>>(q, k, v, Wi, bi, Wf, bf, ipre, fpre);
  scan_kernel<<<16, 256, 0, stream>>>(ipre, fpre, garr, Marr, bsum, Gt);
  convert_kernel<<<dim3(16, 16), 256, 0, stream>>>(k, v, garr, Gt, kh, vt);
  attn_kernel<<<dim3(16, 32), 256, 0, stream>>>(q, kh, vt, Marr, bsum, Gt,
                                                ln_w, ln_b, (float*)d_out);
}

// Round 9
// 83.054 us; speedup vs baseline: 1.2037x; 1.1528x over previous
//
#include <hip/hip_runtime.h>
#include <cstddef>
#include <cstdint>

#define S_LEN 2048
#define D_DIM 512
#define NHEAD 4
#define DHEAD 128
#define BH_CNT 16
#define SCALE_QK 0.08838834764831845f

typedef _Float16 f16;
typedef _Float16 f16x8 __attribute__((ext_vector_type(8)));
typedef float f32x16 __attribute__((ext_vector_type(16)));

__device__ __forceinline__ unsigned pkh(float a, float b) {
  auto r = __builtin_amdgcn_cvt_pkrtz(a, b);   // __fp16 ext_vector_type(2)
  return __builtin_bit_cast(unsigned, r);
}

// ---------------- Kernel 1: gate preactivations ----------------
__global__ __launch_bounds__(256) void gate_kernel(
    const float* __restrict__ q, const float* __restrict__ k, const float* __restrict__ v,
    const float* __restrict__ Wi, const float* __restrict__ bi,
    const float* __restrict__ Wf, const float* __restrict__ bf,
    float* __restrict__ ipre, float* __restrict__ fpre)
{
  const int wave = threadIdx.x >> 6;
  const int lane = threadIdx.x & 63;
  const int pos  = blockIdx.x * 4 + wave;
  const int b = pos >> 11;
  const int s = pos & 2047;
  const float* qp = q + (size_t)pos * D_DIM;
  const float* kp = k + (size_t)pos * D_DIM;
  const float* vp = v + (size_t)pos * D_DIM;

  float acc[8] = {0.f,0.f,0.f,0.f,0.f,0.f,0.f,0.f};
  #pragma unroll
  for (int j = 0; j < 24; ++j) {
    int e = lane + (j << 6);
    float x;
    if (e < 512)       x = qp[e];
    else if (e < 1024) x = kp[e - 512];
    else               x = vp[e - 1024];
    #pragma unroll
    for (int h = 0; h < 4; ++h) {
      acc[h]     = fmaf(x, Wi[h * 1536 + e], acc[h]);
      acc[4 + h] = fmaf(x, Wf[h * 1536 + e], acc[4 + h]);
    }
  }
  #pragma unroll
  for (int off = 32; off > 0; off >>= 1) {
    #pragma unroll
    for (int a = 0; a < 8; ++a) acc[a] += __shfl_down(acc[a], off);
  }
  if (lane == 0) {
    #pragma unroll
    for (int h = 0; h < 4; ++h) {
      ipre[(size_t)(b * 4 + h) * S_LEN + s] = acc[h] + bi[h];
      fpre[(size_t)(b * 4 + h) * S_LEN + s] = acc[4 + h] + bf[h];
    }
  }
}

// ---------------- Kernel 2: single-pass register scans ----------------
__global__ __launch_bounds__(256) void scan_kernel(
    const float* __restrict__ ipre, const float* __restrict__ fpre,
    float* __restrict__ g_out, float* __restrict__ M_out,
    float* __restrict__ bsum_out, float* __restrict__ Gt_out)
{
  __shared__ float wsh[8];
  const int bh = blockIdx.x;
  const int tid = threadIdx.x, lane = tid & 63, wv = tid >> 6;
  const int base = tid * 8;
  const float* fp = fpre + (size_t)bh * S_LEN;
  const float* ip = ipre + (size_t)bh * S_LEN;

  float x[8], ls[8];
  float4 a0 = *(const float4*)(fp + base), a1 = *(const float4*)(fp + base + 4);
  x[0]=a0.x; x[1]=a0.y; x[2]=a0.z; x[3]=a0.w;
  x[4]=a1.x; x[5]=a1.y; x[6]=a1.z; x[7]=a1.w;
  float run = 0.f;
  #pragma unroll
  for (int i = 0; i < 8; ++i) {
    float lsv = fminf(x[i], 0.f) - log1pf(expf(-fabsf(x[i])));
    run += lsv; ls[i] = run;
  }
  float sc = run;
  #pragma unroll
  for (int off = 1; off < 64; off <<= 1) {
    float o = __shfl_up(sc, off);
    if (lane >= off) sc += o;
  }
  if (lane == 63) wsh[wv] = sc;
  __syncthreads();
  float woff = 0.f;
  #pragma unroll
  for (int u = 0; u < 4; ++u) if (u < wv) woff += wsh[u];
  const float ex = woff + (sc - run);

  float4 i0 = *(const float4*)(ip + base), i1 = *(const float4*)(ip + base + 4);
  float iv[8];
  iv[0]=i0.x; iv[1]=i0.y; iv[2]=i0.z; iv[3]=i0.w;
  iv[4]=i1.x; iv[5]=i1.y; iv[6]=i1.z; iv[7]=i1.w;
  float g[8], bc[8], pm[8];
  float runm = -3.0e38f;
  #pragma unroll
  for (int i = 0; i < 8; ++i) {
    bc[i] = ex + ls[i];
    g[i] = iv[i] - bc[i];
    runm = fmaxf(runm, g[i]);
    pm[i] = runm;
  }
  *(float4*)(bsum_out + (size_t)bh * S_LEN + base)     = make_float4(bc[0],bc[1],bc[2],bc[3]);
  *(float4*)(bsum_out + (size_t)bh * S_LEN + base + 4) = make_float4(bc[4],bc[5],bc[6],bc[7]);
  *(float4*)(g_out + (size_t)bh * S_LEN + base)        = make_float4(g[0],g[1],g[2],g[3]);
  *(float4*)(g_out + (size_t)bh * S_LEN + base + 4)    = make_float4(g[4],g[5],g[6],g[7]);

  float t8 = runm;
  t8 = fmaxf(t8, __shfl_xor(t8, 1));
  t8 = fmaxf(t8, __shfl_xor(t8, 2));
  t8 = fmaxf(t8, __shfl_xor(t8, 4));
  if ((tid & 7) == 0) Gt_out[bh * 32 + (tid >> 3)] = t8;

  float scm = runm;
  #pragma unroll
  for (int off = 1; off < 64; off <<= 1) {
    float o = __shfl_up(scm, off);
    if (lane >= off) scm = fmaxf(scm, o);
  }
  if (lane == 63) wsh[4 + wv] = scm;
  __syncthreads();
  float wmo = -3.0e38f;
  #pragma unroll
  for (int u = 0; u < 4; ++u) if (u < wv) wmo = fmaxf(wmo, wsh[4 + u]);
  float prev = __shfl_up(scm, 1);
  if (lane == 0) prev = -3.0e38f;
  const float exm = fmaxf(wmo, prev);
  float M[8];
  #pragma unroll
  for (int i = 0; i < 8; ++i) M[i] = fmaxf(exm, pm[i]);
  *(float4*)(M_out + (size_t)bh * S_LEN + base)     = make_float4(M[0],M[1],M[2],M[3]);
  *(float4*)(M_out + (size_t)bh * S_LEN + base + 4) = make_float4(M[4],M[5],M[6],M[7]);
}

// ---------------- Kernel 3: fp16 conversion into fragment-linear layout ------
// khat tile (bh,kt64), 16KB, 16B units: unit((s>>5)*8+ks)*2+hi)*32+(s&31))
//   holds k[s, ks*16+hi*8 .. +8] * exp(g[s]-Gt[kt])
// vT tile (bh,kt64), 16KB: unit(((d>>5)*4+c)*2+hi)*32+(d&31))
//   holds v[s0..s0+8, d], s0 = (c*2+hi)*8
__global__ __launch_bounds__(256) void convert_kernel(
    const float* __restrict__ k, const float* __restrict__ v,
    const float* __restrict__ g_arr, const float* __restrict__ Gt_arr,
    char* __restrict__ khat, char* __restrict__ vT)
{
  const int kt = blockIdx.x;     // 64-row tile
  const int bh = blockIdx.y;
  const int b = bh >> 2, hh = bh & 3;
  const int tid = threadIdx.x;
  char* ktile = khat + (size_t)(bh * 32 + kt) * 16384;
  char* vtile = vT   + (size_t)(bh * 32 + kt) * 16384;
  const float Gtv = Gt_arr[bh * 32 + kt];

  // K part: coalesced row reads (16 lanes cover one 512B row)
  {
    const int dc8 = tid & 15;          // d-chunk of 8
    const int s4  = tid >> 4;          // 0..15
    const int ks = dc8 >> 1, hi = dc8 & 1;
    #pragma unroll
    for (int jj = 0; jj < 4; ++jj) {
      const int s = s4 + 16 * jj;      // 0..63
      const int sg = kt * 64 + s;
      const float cf = __expf(g_arr[(size_t)bh * S_LEN + sg] - Gtv);
      const float* kr = k + ((size_t)(b * S_LEN + sg)) * D_DIM + hh * DHEAD + dc8 * 8;
      float4 x0 = *(const float4*)kr;
      float4 x1 = *(const float4*)(kr + 4);
      uint4 u;
      u.x = pkh(x0.x * cf, x0.y * cf);
      u.y = pkh(x0.z * cf, x0.w * cf);
      u.z = pkh(x1.x * cf, x1.y * cf);
      u.w = pkh(x1.z * cf, x1.w * cf);
      const int unit = (((s >> 5) * 8 + ks) * 2 + hi) * 32 + (s & 31);
      *(uint4*)(ktile + unit * 16) = u;
    }
  }
  // V part: column gather (coalesced across d)
  {
    const int d   = tid & 127;
    const int scg = tid >> 7;          // 0..1
    const int df = d >> 5, lo = d & 31;
    #pragma unroll
    for (int jj = 0; jj < 4; ++jj) {
      const int sc8 = scg + 2 * jj;    // 0..7
      const int c = sc8 >> 1, hi = sc8 & 1;
      const float* vr = v + ((size_t)(b * S_LEN + kt * 64 + sc8 * 8)) * D_DIM + hh * DHEAD + d;
      float vv[8];
      #pragma unroll
      for (int t = 0; t < 8; ++t) vv[t] = vr[(size_t)t * D_DIM];
      uint4 u;
      u.x = pkh(vv[0], vv[1]); u.y = pkh(vv[2], vv[3]);
      u.z = pkh(vv[4], vv[5]); u.w = pkh(vv[6], vv[7]);
      const int unit = ((df * 4 + c) * 2 + hi) * 32 + lo;
      *(uint4*)(vtile + unit * 16) = u;
    }
  }
}

// ---------------- Kernel 4: barrier-free MFMA attention (L2-direct) ----------
// 32-row q-tiles j in 0..63; block (bh,p) processes pair (63-p, p).
// grid (16,32) bh-major -> flat%8 == bh%8 (XCD-local K/V, L2-served).
// 4 waves (sh, dh) fully independent in the main loop: K/V frags read straight
// from L2 (fragment-linear layout, coalesced). K double-buffered in regs one
// step ahead; V loaded at step top, consumed after QK. No LDS / barriers until
// the epilogue combine.
__global__ __launch_bounds__(256, 2) void attn_kernel(
    const float* __restrict__ q, const char* __restrict__ khat, const char* __restrict__ vT,
    const float* __restrict__ M_arr, const float* __restrict__ bs_arr,
    const float* __restrict__ Gt_arr,
    const float* __restrict__ ln_w, const float* __restrict__ ln_b,
    float* __restrict__ out)
{
  __shared__ float cb[4416];          // epilogue combine (17.7 KB)
  const int bh = blockIdx.x;
  const int p  = blockIdx.y;          // 0..31
  const int b = bh >> 2, hh = bh & 3;
  const int tid = threadIdx.x;
  const int w = tid >> 6, lane = tid & 63, lo = lane & 31, hi = lane >> 5;
  const int sh = w & 1, dh = w >> 1;

  const char* gk = khat + (size_t)bh * 524288;
  const char* gv = vT   + (size_t)bh * 524288;
  const float* Mb  = M_arr  + (size_t)bh * S_LEN;
  const float* bsb = bs_arr + (size_t)bh * S_LEN;
  const float* Gtb = Gt_arr + bh * 32;

  const float GtReg = Gtb[lo];        // lane i holds Gt[i]

  // fragment base offsets (bytes)
  const int koffB = ((sh * 16 + hi) * 32 + lo) * 16;           // +ks*1024
  const int voffB = (((8 * dh + 2 * sh) * 2 + hi) * 32 + lo) * 16; // +ks2*1024, +dfi*4096

  for (int half = 0; half < 2; ++half) {
    const int j  = half ? p : (63 - p);
    const int tg = 32 * j + lo;
    const float Mt = Mb[tg];
    const float em = __expf(-(bsb[tg] + Mt));
    const float M0 = Mb[32 * j];
    const int ktLast = (32 * j + 31) >> 6;
    int kts = 0;
    while (kts < ktLast && Gtb[kts] < M0 - 25.f) ++kts;

    // Q fragments from fp32 global (once per tile)
    f16x8 qf[8];
    const float* qrow = q + ((size_t)(b * S_LEN + tg)) * D_DIM + hh * DHEAD;
    #pragma unroll
    for (int ks = 0; ks < 8; ++ks) {
      const int d0 = ks * 16 + hi * 8;
      float4 x0 = *(const float4*)(qrow + d0);
      float4 x1 = *(const float4*)(qrow + d0 + 4);
      uint4 u;
      u.x = pkh(x0.x * SCALE_QK, x0.y * SCALE_QK);
      u.y = pkh(x0.z * SCALE_QK, x0.w * SCALE_QK);
      u.z = pkh(x1.x * SCALE_QK, x1.y * SCALE_QK);
      u.w = pkh(x1.z * SCALE_QK, x1.w * SCALE_QK);
      qf[ks] = __builtin_bit_cast(f16x8, u);
    }

    f32x16 h0 = {}, h1 = {};
    float rowsum = 0.f;

    auto load_k = [&](uint4* kf, int kt2) {
      const char* kb = gk + (size_t)kt2 * 16384;
      #pragma unroll
      for (int ks = 0; ks < 8; ++ks)
        kf[ks] = *(const uint4*)(kb + koffB + ks * 1024);
    };

    auto step = [&](int kt2, uint4* kf, uint4* kfn, bool pref) {
      const char* vb2 = gv + (size_t)kt2 * 16384;
      uint4 vf0 = *(const uint4*)(vb2 + voffB);
      uint4 vf1 = *(const uint4*)(vb2 + voffB + 1024);
      uint4 vf2 = *(const uint4*)(vb2 + voffB + 4096);
      uint4 vf3 = *(const uint4*)(vb2 + voffB + 5120);
      if (pref) load_k(kfn, kt2 + 1);
      const float Gtv = __shfl(GtReg, kt2);
      const float rf = __expf(Gtv - Mt);
      f32x16 sacc0 = {}, sacc1 = {};
      __builtin_amdgcn_s_setprio(1);
      #pragma unroll
      for (int ks = 0; ks < 4; ++ks) {
        sacc0 = __builtin_amdgcn_mfma_f32_32x32x16_f16(
            __builtin_bit_cast(f16x8, kf[2 * ks]), qf[2 * ks], sacc0, 0, 0, 0);
        sacc1 = __builtin_amdgcn_mfma_f32_32x32x16_f16(
            __builtin_bit_cast(f16x8, kf[2 * ks + 1]), qf[2 * ks + 1], sacc1, 0, 0, 0);
      }
      __builtin_amdgcn_s_setprio(0);
      const int bnd = tg - 64 * kt2;
      float vals[16];
      float tsum = 0.f;
      #pragma unroll
      for (int r = 0; r < 16; ++r) {
        float val = (sacc0[r] + sacc1[r]) * rf;
        int sl = 32 * sh + (r & 3) + 8 * (r >> 2) + 4 * hi;
        if (sl > bnd) val = 0.f;
        tsum += val;
        vals[r] = val;
      }
      rowsum += tsum + __shfl_xor(tsum, 32);
      uint32_t a0 = pkh(vals[0], vals[1]),   a1 = pkh(vals[2], vals[3]);
      uint32_t a2 = pkh(vals[4], vals[5]),   a3 = pkh(vals[6], vals[7]);
      uint32_t b0 = pkh(vals[8], vals[9]),   b1 = pkh(vals[10], vals[11]);
      uint32_t b2 = pkh(vals[12], vals[13]), b3 = pkh(vals[14], vals[15]);
      uint32_t sa0 = __shfl_xor(a0, 32), sa1 = __shfl_xor(a1, 32);
      uint32_t sa2 = __shfl_xor(a2, 32), sa3 = __shfl_xor(a3, 32);
      uint32_t sb0 = __shfl_xor(b0, 32), sb1 = __shfl_xor(b1, 32);
      uint32_t sb2 = __shfl_xor(b2, 32), sb3 = __shfl_xor(b3, 32);
      uint4 f0, f1;
      f0.x = hi ? sa2 : a0;  f0.y = hi ? sa3 : a1;
      f0.z = hi ? a2 : sa0;  f0.w = hi ? a3 : sa1;
      f1.x = hi ? sb2 : b0;  f1.y = hi ? sb3 : b1;
      f1.z = hi ? b2 : sb0;  f1.w = hi ? b3 : sb1;
      f16x8 f0h = __builtin_bit_cast(f16x8, f0);
      f16x8 f1h = __builtin_bit_cast(f16x8, f1);
      __builtin_amdgcn_s_setprio(1);
      h0 = __builtin_amdgcn_mfma_f32_32x32x16_f16(__builtin_bit_cast(f16x8, vf0), f0h, h0, 0, 0, 0);
      h0 = __builtin_amdgcn_mfma_f32_32x32x16_f16(__builtin_bit_cast(f16x8, vf1), f1h, h0, 0, 0, 0);
      h1 = __builtin_amdgcn_mfma_f32_32x32x16_f16(__builtin_bit_cast(f16x8, vf2), f0h, h1, 0, 0, 0);
      h1 = __builtin_amdgcn_mfma_f32_32x32x16_f16(__builtin_bit_cast(f16x8, vf3), f1h, h1, 0, 0, 0);
      __builtin_amdgcn_s_setprio(0);
    };

    uint4 ka[8], kb2[8];
    load_k(ka, kts);
    for (int kt = kts; kt <= ktLast; kt += 2) {
      step(kt, ka, kb2, kt + 1 <= ktLast);
      if (kt + 1 > ktLast) break;
      step(kt + 1, kb2, ka, kt + 2 <= ktLast);
    }

    // ---- combine s-halves + epilogue ----
    if (sh == 1) {
      #pragma unroll
      for (int r = 0; r < 16; ++r) {
        cb[(dh * 2 + 0) * 1024 + r * 64 + lane] = h0[r];
        cb[(dh * 2 + 1) * 1024 + r * 64 + lane] = h1[r];
      }
      if (dh == 0) cb[4096 + lane] = rowsum;
    }
    __syncthreads();
    float s1 = 0.f, s2 = 0.f;
    if (sh == 0) {
      #pragma unroll
      for (int r = 0; r < 16; ++r) {
        h0[r] += cb[(dh * 2 + 0) * 1024 + r * 64 + lane];
        h1[r] += cb[(dh * 2 + 1) * 1024 + r * 64 + lane];
      }
      rowsum += cb[4096 + lane];
      float n = fmaxf(fabsf(rowsum), em);
      float invn = 1.f / (n + 5e-5f);
      #pragma unroll
      for (int r = 0; r < 16; ++r) {
        float x0 = h0[r] * invn, x1 = h1[r] * invn;
        h0[r] = x0; h1[r] = x1;
        s1 += x0 + x1; s2 += x0 * x0 + x1 * x1;
      }
      s1 += __shfl_xor(s1, 32);
      s2 += __shfl_xor(s2, 32);
      cb[4160 + dh * 64 + lane] = s1;
      cb[4288 + dh * 64 + lane] = s2;
    }
    __syncthreads();
    if (sh == 0) {
      s1 += cb[4160 + (dh ^ 1) * 64 + lane];
      s2 += cb[4288 + (dh ^ 1) * 64 + lane];
      float mu = s1 * (1.f / 128.f);
      float var = s2 * (1.f / 128.f) - mu * mu;
      float rstd = rsqrtf(var + 1e-3f);
      float* orow = out + ((size_t)(b * S_LEN) + tg) * D_DIM + hh * DHEAD;
      #pragma unroll
      for (int dfi = 0; dfi < 2; ++dfi) {
        #pragma unroll
        for (int rq = 0; rq < 4; ++rq) {
          int dbase = 64 * dh + 32 * dfi + 8 * rq + 4 * hi;
          float4 wv = *(const float4*)(ln_w + hh * DHEAD + dbase);
          float4 bv = *(const float4*)(ln_b + hh * DHEAD + dbase);
          float v0 = dfi ? h1[rq * 4 + 0] : h0[rq * 4 + 0];
          float v1 = dfi ? h1[rq * 4 + 1] : h0[rq * 4 + 1];
          float v2 = dfi ? h1[rq * 4 + 2] : h0[rq * 4 + 2];
          float v3 = dfi ? h1[rq * 4 + 3] : h0[rq * 4 + 3];
          float4 o;
          o.x = (v0 - mu) * rstd * (1.f + wv.x) + bv.x;
          o.y = (v1 - mu) * rstd * (1.f + wv.y) + bv.y;
          o.z = (v2 - mu) * rstd * (1.f + wv.z) + bv.z;
          o.w = (v3 - mu) * rstd * (1.f + wv.w) + bv.w;
          *(float4*)(orow + dbase) = o;
        }
      }
    }
    __syncthreads();   // cb reused next half
  }
}

extern "C" void kernel_launch(void* const* d_in, const int* in_sizes, int n_in,
                              void* d_out, int out_size, void* d_ws, size_t ws_size,
                              hipStream_t stream) {
  (void)in_sizes; (void)n_in; (void)out_size; (void)ws_size;
  const float* q    = (const float*)d_in[0];
  const float* k    = (const float*)d_in[1];
  const float* v    = (const float*)d_in[2];
  const float* Wi   = (const float*)d_in[3];
  const float* bi   = (const float*)d_in[4];
  const float* Wf   = (const float*)d_in[5];
  const float* bf   = (const float*)d_in[6];
  const float* ln_w = (const float*)d_in[7];
  const float* ln_b = (const float*)d_in[8];

  char* wsb = (char*)d_ws;
  float* ipre = (float*)(wsb + 0);
  float* fpre = (float*)(wsb + 131072);
  float* garr = (float*)(wsb + 262144);
  float* Marr = (float*)(wsb + 393216);
  float* bsum = (float*)(wsb + 524288);
  float* Gt   = (float*)(wsb + 655360);       // 16*32 floats
  char* kh = wsb + 1048576;
  char* vt = wsb + 1048576 + 8388608;

  gate_kernel<<<2048, 256, 0, stream>>>(q, k, v, Wi, bi, Wf, bf, ipre, fpre);
  scan_kernel<<<16, 256, 0, stream>>>(ipre, fpre, garr, Marr, bsum, Gt);
  convert_kernel<<<dim3(32, 16), 256, 0, stream>>>(k, v, garr, Gt, kh, vt);
  attn_kernel<<<dim3(16, 32), 256, 0, stream>>>(q, kh, vt, Marr, bsum, Gt,
                                                ln_w, ln_b, (float*)d_out);
}

// Round 10
// 78.971 us; speedup vs baseline: 1.2659x; 1.0517x over previous
//
#include <hip/hip_runtime.h>
#include <cstddef>
#include <cstdint>

#define S_LEN 2048
#define D_DIM 512
#define NHEAD 4
#define DHEAD 128
#define BH_CNT 16
#define SCALE_QK 0.08838834764831845f

typedef _Float16 f16;
typedef _Float16 f16x8 __attribute__((ext_vector_type(8)));
typedef float f32x16 __attribute__((ext_vector_type(16)));

__device__ __forceinline__ unsigned pkh(float a, float b) {
  auto r = __builtin_amdgcn_cvt_pkrtz(a, b);   // __fp16 ext_vector_type(2)
  return __builtin_bit_cast(unsigned, r);
}

// ---------------- Kernel 1: gate preactivations ----------------
__global__ __launch_bounds__(256) void gate_kernel(
    const float* __restrict__ q, const float* __restrict__ k, const float* __restrict__ v,
    const float* __restrict__ Wi, const float* __restrict__ bi,
    const float* __restrict__ Wf, const float* __restrict__ bf,
    float* __restrict__ ipre, float* __restrict__ fpre)
{
  const int wave = threadIdx.x >> 6;
  const int lane = threadIdx.x & 63;
  const int pos  = blockIdx.x * 4 + wave;
  const int b = pos >> 11;
  const int s = pos & 2047;
  const float* qp = q + (size_t)pos * D_DIM;
  const float* kp = k + (size_t)pos * D_DIM;
  const float* vp = v + (size_t)pos * D_DIM;

  float acc[8] = {0.f,0.f,0.f,0.f,0.f,0.f,0.f,0.f};
  #pragma unroll
  for (int j = 0; j < 24; ++j) {
    int e = lane + (j << 6);
    float x;
    if (e < 512)       x = qp[e];
    else if (e < 1024) x = kp[e - 512];
    else               x = vp[e - 1024];
    #pragma unroll
    for (int h = 0; h < 4; ++h) {
      acc[h]     = fmaf(x, Wi[h * 1536 + e], acc[h]);
      acc[4 + h] = fmaf(x, Wf[h * 1536 + e], acc[4 + h]);
    }
  }
  #pragma unroll
  for (int off = 32; off > 0; off >>= 1) {
    #pragma unroll
    for (int a = 0; a < 8; ++a) acc[a] += __shfl_down(acc[a], off);
  }
  if (lane == 0) {
    #pragma unroll
    for (int h = 0; h < 4; ++h) {
      ipre[(size_t)(b * 4 + h) * S_LEN + s] = acc[h] + bi[h];
      fpre[(size_t)(b * 4 + h) * S_LEN + s] = acc[4 + h] + bf[h];
    }
  }
}

// ---------------- Kernel 2: single-pass register scans ----------------
__global__ __launch_bounds__(256) void scan_kernel(
    const float* __restrict__ ipre, const float* __restrict__ fpre,
    float* __restrict__ g_out, float* __restrict__ M_out,
    float* __restrict__ bsum_out, float* __restrict__ Gt_out)
{
  __shared__ float wsh[8];
  const int bh = blockIdx.x;
  const int tid = threadIdx.x, lane = tid & 63, wv = tid >> 6;
  const int base = tid * 8;
  const float* fp = fpre + (size_t)bh * S_LEN;
  const float* ip = ipre + (size_t)bh * S_LEN;

  float x[8], ls[8];
  float4 a0 = *(const float4*)(fp + base), a1 = *(const float4*)(fp + base + 4);
  x[0]=a0.x; x[1]=a0.y; x[2]=a0.z; x[3]=a0.w;
  x[4]=a1.x; x[5]=a1.y; x[6]=a1.z; x[7]=a1.w;
  float run = 0.f;
  #pragma unroll
  for (int i = 0; i < 8; ++i) {
    float lsv = fminf(x[i], 0.f) - log1pf(expf(-fabsf(x[i])));
    run += lsv; ls[i] = run;
  }
  float sc = run;
  #pragma unroll
  for (int off = 1; off < 64; off <<= 1) {
    float o = __shfl_up(sc, off);
    if (lane >= off) sc += o;
  }
  if (lane == 63) wsh[wv] = sc;
  __syncthreads();
  float woff = 0.f;
  #pragma unroll
  for (int u = 0; u < 4; ++u) if (u < wv) woff += wsh[u];
  const float ex = woff + (sc - run);

  float4 i0 = *(const float4*)(ip + base), i1 = *(const float4*)(ip + base + 4);
  float iv[8];
  iv[0]=i0.x; iv[1]=i0.y; iv[2]=i0.z; iv[3]=i0.w;
  iv[4]=i1.x; iv[5]=i1.y; iv[6]=i1.z; iv[7]=i1.w;
  float g[8], bc[8], pm[8];
  float runm = -3.0e38f;
  #pragma unroll
  for (int i = 0; i < 8; ++i) {
    bc[i] = ex + ls[i];
    g[i] = iv[i] - bc[i];
    runm = fmaxf(runm, g[i]);
    pm[i] = runm;
  }
  *(float4*)(bsum_out + (size_t)bh * S_LEN + base)     = make_float4(bc[0],bc[1],bc[2],bc[3]);
  *(float4*)(bsum_out + (size_t)bh * S_LEN + base + 4) = make_float4(bc[4],bc[5],bc[6],bc[7]);
  *(float4*)(g_out + (size_t)bh * S_LEN + base)        = make_float4(g[0],g[1],g[2],g[3]);
  *(float4*)(g_out + (size_t)bh * S_LEN + base + 4)    = make_float4(g[4],g[5],g[6],g[7]);

  float t8 = runm;
  t8 = fmaxf(t8, __shfl_xor(t8, 1));
  t8 = fmaxf(t8, __shfl_xor(t8, 2));
  t8 = fmaxf(t8, __shfl_xor(t8, 4));
  if ((tid & 7) == 0) Gt_out[bh * 32 + (tid >> 3)] = t8;

  float scm = runm;
  #pragma unroll
  for (int off = 1; off < 64; off <<= 1) {
    float o = __shfl_up(scm, off);
    if (lane >= off) scm = fmaxf(scm, o);
  }
  if (lane == 63) wsh[4 + wv] = scm;
  __syncthreads();
  float wmo = -3.0e38f;
  #pragma unroll
  for (int u = 0; u < 4; ++u) if (u < wv) wmo = fmaxf(wmo, wsh[4 + u]);
  float prev = __shfl_up(scm, 1);
  if (lane == 0) prev = -3.0e38f;
  const float exm = fmaxf(wmo, prev);
  float M[8];
  #pragma unroll
  for (int i = 0; i < 8; ++i) M[i] = fmaxf(exm, pm[i]);
  *(float4*)(M_out + (size_t)bh * S_LEN + base)     = make_float4(M[0],M[1],M[2],M[3]);
  *(float4*)(M_out + (size_t)bh * S_LEN + base + 4) = make_float4(M[4],M[5],M[6],M[7]);
}

// ---------------- Kernel 3: fp16 conversion, fragment-linear, XCD-matched ----
// grid (bh=16, kt=32) bh-major -> writes flow through XCD bh%8's L2, same
// XCD attn reads from.
// qhat/khat tile (bh,kt64), 16KB, 16B units: unit(((s>>5)*8+ks)*2+hi)*32+(s&31)
//   khat holds k * exp(g-Gt); qhat holds q * SCALE_QK
// vT tile: unit(((d>>5)*4+c)*2+hi2)*32+(d&31) holds v[s0..s0+8, d], s0=(2c+hi2)*8
__global__ __launch_bounds__(256) void convert_kernel(
    const float* __restrict__ q, const float* __restrict__ k, const float* __restrict__ v,
    const float* __restrict__ g_arr, const float* __restrict__ Gt_arr,
    char* __restrict__ qhat, char* __restrict__ khat, char* __restrict__ vT)
{
  const int bh = blockIdx.x;
  const int kt = blockIdx.y;     // 64-row tile
  const int b = bh >> 2, hh = bh & 3;
  const int tid = threadIdx.x;
  const size_t tb = (size_t)(bh * 32 + kt) * 16384;
  char* ktile = khat + tb;
  char* qtile = qhat + tb;
  char* vtile = vT + tb;
  const float Gtv = Gt_arr[bh * 32 + kt];

  // K + Q part: coalesced row reads (16 lanes cover one 512B row)
  {
    const int dc8 = tid & 15;          // d-chunk of 8
    const int s4  = tid >> 4;          // 0..15
    const int ks = dc8 >> 1, hi = dc8 & 1;
    #pragma unroll
    for (int jj = 0; jj < 4; ++jj) {
      const int s = s4 + 16 * jj;      // 0..63
      const int sg = kt * 64 + s;
      const float cf = __expf(g_arr[(size_t)bh * S_LEN + sg] - Gtv);
      const int unit = (((s >> 5) * 8 + ks) * 2 + hi) * 32 + (s & 31);
      const float* kr = k + ((size_t)(b * S_LEN + sg)) * D_DIM + hh * DHEAD + dc8 * 8;
      float4 x0 = *(const float4*)kr;
      float4 x1 = *(const float4*)(kr + 4);
      uint4 u;
      u.x = pkh(x0.x * cf, x0.y * cf);
      u.y = pkh(x0.z * cf, x0.w * cf);
      u.z = pkh(x1.x * cf, x1.y * cf);
      u.w = pkh(x1.z * cf, x1.w * cf);
      *(uint4*)(ktile + unit * 16) = u;
      const float* qr = q + ((size_t)(b * S_LEN + sg)) * D_DIM + hh * DHEAD + dc8 * 8;
      float4 y0 = *(const float4*)qr;
      float4 y1 = *(const float4*)(qr + 4);
      uint4 uq;
      uq.x = pkh(y0.x * SCALE_QK, y0.y * SCALE_QK);
      uq.y = pkh(y0.z * SCALE_QK, y0.w * SCALE_QK);
      uq.z = pkh(y1.x * SCALE_QK, y1.y * SCALE_QK);
      uq.w = pkh(y1.z * SCALE_QK, y1.w * SCALE_QK);
      *(uint4*)(qtile + unit * 16) = uq;
    }
  }
  // V part: column gather (coalesced across d)
  {
    const int d   = tid & 127;
    const int scg = tid >> 7;          // 0..1
    const int df = d >> 5, lo = d & 31;
    #pragma unroll
    for (int jj = 0; jj < 4; ++jj) {
      const int sc8 = scg + 2 * jj;    // 0..7
      const int c = sc8 >> 1, hi = sc8 & 1;
      const float* vr = v + ((size_t)(b * S_LEN + kt * 64 + sc8 * 8)) * D_DIM + hh * DHEAD + d;
      float vv[8];
      #pragma unroll
      for (int t = 0; t < 8; ++t) vv[t] = vr[(size_t)t * D_DIM];
      uint4 u;
      u.x = pkh(vv[0], vv[1]); u.y = pkh(vv[2], vv[3]);
      u.z = pkh(vv[4], vv[5]); u.w = pkh(vv[6], vv[7]);
      const int unit = ((df * 4 + c) * 2 + hi) * 32 + lo;
      *(uint4*)(vtile + unit * 16) = u;
    }
  }
}

// ---------------- Kernel 4: barrier-free MFMA attention, 128-kt steps --------
// 32-row q-tiles j in 0..63; block (bh,p) processes pair (63-p, p).
// grid (16,32) bh-major -> flat%8 == bh%8 (XCD-local K/V/Q, L2-resident).
// 4 waves = 4-way s-split of the 128-kt tile (NO QK duplication); each wave
// computes full-128d partial h for its 32-s quarter. Epilogue: waves 1-3 dump
// h to LDS, wave 0 combines + n + LN + store.
__global__ __launch_bounds__(256, 2) void attn_kernel(
    const char* __restrict__ qhat, const char* __restrict__ khat, const char* __restrict__ vT,
    const float* __restrict__ M_arr, const float* __restrict__ bs_arr,
    const float* __restrict__ Gt_arr,
    const float* __restrict__ ln_w, const float* __restrict__ ln_b,
    float* __restrict__ out)
{
  __shared__ float cb[12480];         // 3 waves x (4x16x64) h + 3x64 rowsum = 49.9KB
  const int bh = blockIdx.x;
  const int p  = blockIdx.y;          // 0..31
  const int b = bh >> 2, hh = bh & 3;
  const int tid = threadIdx.x;
  const int w = tid >> 6, lane = tid & 63, lo = lane & 31, hi = lane >> 5;
  const int sh = w;                   // s-quarter 0..3
  const int s64 = sh >> 1, s32 = sh & 1;
  const int lb16 = (hi * 32 + lo) * 16;

  const char* gq = qhat + (size_t)bh * 524288;
  const char* gk = khat + (size_t)bh * 524288;
  const char* gv = vT   + (size_t)bh * 524288;
  const float* Mb  = M_arr  + (size_t)bh * S_LEN;
  const float* bsb = bs_arr + (size_t)bh * S_LEN;
  const float* Gtb = Gt_arr + bh * 32;

  const float GtReg = Gtb[lo];        // lane i holds Gt64[i]

  for (int half = 0; half < 2; ++half) {
    const int j  = half ? p : (63 - p);
    const int tg = 32 * j + lo;
    const float Mt = Mb[tg];
    const float em = __expf(-(bsb[tg] + Mt));
    const float M0 = Mb[32 * j];
    const int ktLast = (32 * j + 31) >> 7;     // 128-kt tiles
    int kts = 0;
    while (kts < ktLast &&
           fmaxf(Gtb[2 * kts], Gtb[2 * kts + 1]) < M0 - 25.f) ++kts;

    // Q fragments: coalesced from qhat (1KB per frag per wave)
    f16x8 qf[8];
    const char* qt = gq + (size_t)(j >> 1) * 16384;
    #pragma unroll
    for (int ks = 0; ks < 8; ++ks)
      qf[ks] = *(const f16x8*)(qt + ((j & 1) * 8 + ks) * 1024 + lb16);

    f32x16 h0 = {}, h1 = {}, h2 = {}, h3 = {};
    float rowsum = 0.f;

    for (int kt = kts; kt <= ktLast; ++kt) {
      const char* kb = gk + (size_t)(2 * kt + s64) * 16384;
      const char* vb = gv + (size_t)(2 * kt + s64) * 16384;
      uint4 kf[8], vf[8];
      #pragma unroll
      for (int ks = 0; ks < 8; ++ks)
        kf[ks] = *(const uint4*)(kb + (s32 * 8 + ks) * 1024 + lb16);
      #pragma unroll
      for (int df = 0; df < 4; ++df)
        #pragma unroll
        for (int ks2 = 0; ks2 < 2; ++ks2)
          vf[df * 2 + ks2] = *(const uint4*)(vb + ((df * 4 + 2 * s32 + ks2)) * 1024 + lb16);

      const float Gtv = __shfl(GtReg, 2 * kt + s64);
      const float rf = __expf(Gtv - Mt);

      f32x16 sacc0 = {}, sacc1 = {};
      __builtin_amdgcn_s_setprio(1);
      #pragma unroll
      for (int ks = 0; ks < 4; ++ks) {
        sacc0 = __builtin_amdgcn_mfma_f32_32x32x16_f16(
            __builtin_bit_cast(f16x8, kf[2 * ks]), qf[2 * ks], sacc0, 0, 0, 0);
        sacc1 = __builtin_amdgcn_mfma_f32_32x32x16_f16(
            __builtin_bit_cast(f16x8, kf[2 * ks + 1]), qf[2 * ks + 1], sacc1, 0, 0, 0);
      }
      __builtin_amdgcn_s_setprio(0);

      const bool last = (kt == ktLast);
      const int bnd = tg - 128 * kt;
      float tsum = 0.f;
      uint32_t pk[8];
      #pragma unroll
      for (int rr = 0; rr < 8; ++rr) {
        float v0 = (sacc0[2 * rr] + sacc1[2 * rr]) * rf;
        float v1 = (sacc0[2 * rr + 1] + sacc1[2 * rr + 1]) * rf;
        if (last) {
          int sl0 = 32 * sh + ((2 * rr) & 3) + 8 * (rr >> 1) + 4 * hi;
          if (sl0 > bnd) v0 = 0.f;
          if (sl0 + 1 > bnd) v1 = 0.f;
        }
        tsum += v0 + v1;
        pk[rr] = pkh(v0, v1);
      }
      rowsum += tsum + __shfl_xor(tsum, 32);
      uint32_t sw[8];
      #pragma unroll
      for (int rr = 0; rr < 8; ++rr) sw[rr] = __shfl_xor(pk[rr], 32);
      uint4 f0, f1;
      f0.x = hi ? sw[2] : pk[0];  f0.y = hi ? sw[3] : pk[1];
      f0.z = hi ? pk[2] : sw[0];  f0.w = hi ? pk[3] : sw[1];
      f1.x = hi ? sw[6] : pk[4];  f1.y = hi ? sw[7] : pk[5];
      f1.z = hi ? pk[6] : sw[4];  f1.w = hi ? pk[7] : sw[5];
      f16x8 f0h = __builtin_bit_cast(f16x8, f0);
      f16x8 f1h = __builtin_bit_cast(f16x8, f1);

      __builtin_amdgcn_s_setprio(1);
      h0 = __builtin_amdgcn_mfma_f32_32x32x16_f16(__builtin_bit_cast(f16x8, vf[0]), f0h, h0, 0, 0, 0);
      h1 = __builtin_amdgcn_mfma_f32_32x32x16_f16(__builtin_bit_cast(f16x8, vf[2]), f0h, h1, 0, 0, 0);
      h2 = __builtin_amdgcn_mfma_f32_32x32x16_f16(__builtin_bit_cast(f16x8, vf[4]), f0h, h2, 0, 0, 0);
      h3 = __builtin_amdgcn_mfma_f32_32x32x16_f16(__builtin_bit_cast(f16x8, vf[6]), f0h, h3, 0, 0, 0);
      h0 = __builtin_amdgcn_mfma_f32_32x32x16_f16(__builtin_bit_cast(f16x8, vf[1]), f1h, h0, 0, 0, 0);
      h1 = __builtin_amdgcn_mfma_f32_32x32x16_f16(__builtin_bit_cast(f16x8, vf[3]), f1h, h1, 0, 0, 0);
      h2 = __builtin_amdgcn_mfma_f32_32x32x16_f16(__builtin_bit_cast(f16x8, vf[5]), f1h, h2, 0, 0, 0);
      h3 = __builtin_amdgcn_mfma_f32_32x32x16_f16(__builtin_bit_cast(f16x8, vf[7]), f1h, h3, 0, 0, 0);
      __builtin_amdgcn_s_setprio(0);
    }

    // ---- epilogue: waves 1-3 dump partial h; wave 0 combines + LN + store ----
    if (w != 0) {
      const int wb = (w - 1) * 4096;
      #pragma unroll
      for (int r = 0; r < 16; ++r) {
        cb[wb +    0 + r * 64 + lane] = h0[r];
        cb[wb + 1024 + r * 64 + lane] = h1[r];
        cb[wb + 2048 + r * 64 + lane] = h2[r];
        cb[wb + 3072 + r * 64 + lane] = h3[r];
      }
      cb[12288 + (w - 1) * 64 + lane] = rowsum;
    }
    __syncthreads();
    if (w == 0) {
      #pragma unroll
      for (int u = 0; u < 3; ++u) {
        const int ub = u * 4096;
        #pragma unroll
        for (int r = 0; r < 16; ++r) {
          h0[r] += cb[ub +    0 + r * 64 + lane];
          h1[r] += cb[ub + 1024 + r * 64 + lane];
          h2[r] += cb[ub + 2048 + r * 64 + lane];
          h3[r] += cb[ub + 3072 + r * 64 + lane];
        }
      }
      rowsum += cb[12288 + lane] + cb[12352 + lane] + cb[12416 + lane];
      float n = fmaxf(fabsf(rowsum), em);
      float invn = 1.f / (n + 5e-5f);
      float s1 = 0.f, s2 = 0.f;
      #pragma unroll
      for (int r = 0; r < 16; ++r) {
        float x0 = h0[r] * invn, x1 = h1[r] * invn;
        float x2 = h2[r] * invn, x3 = h3[r] * invn;
        h0[r] = x0; h1[r] = x1; h2[r] = x2; h3[r] = x3;
        s1 += x0 + x1 + x2 + x3;
        s2 += x0 * x0 + x1 * x1 + x2 * x2 + x3 * x3;
      }
      s1 += __shfl_xor(s1, 32);
      s2 += __shfl_xor(s2, 32);
      float mu = s1 * (1.f / 128.f);
      float var = s2 * (1.f / 128.f) - mu * mu;
      float rstd = rsqrtf(var + 1e-3f);
      float* orow = out + ((size_t)(b * S_LEN) + tg) * D_DIM + hh * DHEAD;
      #pragma unroll
      for (int df = 0; df < 4; ++df) {
        #pragma unroll
        for (int rq = 0; rq < 4; ++rq) {
          int dbase = 32 * df + 8 * rq + 4 * hi;
          float4 wv = *(const float4*)(ln_w + hh * DHEAD + dbase);
          float4 bv = *(const float4*)(ln_b + hh * DHEAD + dbase);
          float v0, v1, v2, v3;
          if (df == 0)      { v0 = h0[rq*4+0]; v1 = h0[rq*4+1]; v2 = h0[rq*4+2]; v3 = h0[rq*4+3]; }
          else if (df == 1) { v0 = h1[rq*4+0]; v1 = h1[rq*4+1]; v2 = h1[rq*4+2]; v3 = h1[rq*4+3]; }
          else if (df == 2) { v0 = h2[rq*4+0]; v1 = h2[rq*4+1]; v2 = h2[rq*4+2]; v3 = h2[rq*4+3]; }
          else              { v0 = h3[rq*4+0]; v1 = h3[rq*4+1]; v2 = h3[rq*4+2]; v3 = h3[rq*4+3]; }
          float4 o;
          o.x = (v0 - mu) * rstd * (1.f + wv.x) + bv.x;
          o.y = (v1 - mu) * rstd * (1.f + wv.y) + bv.y;
          o.z = (v2 - mu) * rstd * (1.f + wv.z) + bv.z;
          o.w = (v3 - mu) * rstd * (1.f + wv.w) + bv.w;
          *(float4*)(orow + dbase) = o;
        }
      }
    }
    __syncthreads();   // cb reused next half
  }
}

extern "C" void kernel_launch(void* const* d_in, const int* in_sizes, int n_in,
                              void* d_out, int out_size, void* d_ws, size_t ws_size,
                              hipStream_t stream) {
  (void)in_sizes; (void)n_in; (void)out_size; (void)ws_size;
  const float* q    = (const float*)d_in[0];
  const float* k    = (const float*)d_in[1];
  const float* v    = (const float*)d_in[2];
  const float* Wi   = (const float*)d_in[3];
  const float* bi   = (const float*)d_in[4];
  const float* Wf   = (const float*)d_in[5];
  const float* bf   = (const float*)d_in[6];
  const float* ln_w = (const float*)d_in[7];
  const float* ln_b = (const float*)d_in[8];

  char* wsb = (char*)d_ws;
  float* ipre = (float*)(wsb + 0);
  float* fpre = (float*)(wsb + 131072);
  float* garr = (float*)(wsb + 262144);
  float* Marr = (float*)(wsb + 393216);
  float* bsum = (float*)(wsb + 524288);
  float* Gt   = (float*)(wsb + 655360);       // 16*32 floats
  char* kh = wsb + 1048576;                    // 8MB
  char* vt = wsb + 1048576 + 8388608;          // 8MB
  char* qh = wsb + 1048576 + 16777216;         // 8MB

  gate_kernel<<<2048, 256, 0, stream>>>(q, k, v, Wi, bi, Wf, bf, ipre, fpre);
  scan_kernel<<<16, 256, 0, stream>>>(ipre, fpre, garr, Marr, bsum, Gt);
  convert_kernel<<<dim3(16, 32), 256, 0, stream>>>(q, k, v, garr, Gt, qh, kh, vt);
  attn_kernel<<<dim3(16, 32), 256, 0, stream>>>(qh, kh, vt, Marr, bsum, Gt,
                                                ln_w, ln_b, (float*)d_out);
}